// Round 1
// baseline (170.438 us; speedup 1.0000x reference)
//
#include <hip/hip_runtime.h>

#define HID 512
#define SEQ 4096
#define NB 32
#define BS 64
#define NCHUNK (SEQ / BS)   // 64 chunks per batch row
#define CH_STRIDE 514       // [m, den, num[512]]

typedef __attribute__((ext_vector_type(8))) __bf16 bf16x8;
typedef __attribute__((ext_vector_type(16))) float f32x16;

__device__ __forceinline__ unsigned short f2bf(float f) {
    unsigned int u = __float_as_uint(f);
    u += 0x7FFFu + ((u >> 16) & 1u);   // round-to-nearest-even
    return (unsigned short)(u >> 16);
}

// ---- Kernel 1: W1aT[h][k] = bf16(W1[512+k][h]), coalesced via LDS tile ----
__global__ void transpose_w1a(const float* __restrict__ W1,
                              unsigned short* __restrict__ w1at) {
    __shared__ float tile[64][65];
    int t = threadIdx.x;
    int lane = t & 63;
    int r4 = t >> 6;            // 0..3
    int k0 = blockIdx.x * 64;
    int h0 = blockIdx.y * 64;
#pragma unroll
    for (int i = 0; i < 16; ++i) {
        int r = i * 4 + r4;     // k-row within tile
        tile[r][lane] = W1[(size_t)(HID + k0 + r) * HID + h0 + lane];
    }
    __syncthreads();
#pragma unroll
    for (int i = 0; i < 16; ++i) {
        int hr = i * 4 + r4;    // h-row of output
        w1at[(size_t)(h0 + hr) * HID + k0 + lane] = f2bf(tile[lane][hr]);
    }
}

// ---- Kernel 2: pre_part[b][kc][h] = sum_{k in kc-chunk} prev[b][k]*W1_h[k][h] ----
__global__ void pre_partial(const float* __restrict__ prev,
                            const float* __restrict__ W1,
                            float* __restrict__ pre_part) {
    __shared__ float pl[128];
    int kc = blockIdx.x;   // 0..3
    int b  = blockIdx.y;
    int t  = threadIdx.x;
    if (t < 128) pl[t] = prev[b * HID + kc * 128 + t];
    __syncthreads();
    int h0 = 2 * t;
    float ax = 0.f, ay = 0.f;
    for (int k = 0; k < 128; ++k) {
        float pv = pl[k];
        float2 wv = *(const float2*)(W1 + (size_t)(kc * 128 + k) * HID + h0);
        ax += pv * wv.x;
        ay += pv * wv.y;
    }
    float* dst = pre_part + ((size_t)b * 4 + kc) * HID + h0;
    dst[0] = ax; dst[1] = ay;
}

// ---- Kernel 3: fused score GEMM + tanh + w2-reduce + block softmax partials
//      + partial context numerator (flash-style).  grid (64 chunks, 32 b) x 256 ----
__global__ __launch_bounds__(256, 2)
void score_ctx(const float* __restrict__ ann,
               const unsigned short* __restrict__ w1at,
               const float* __restrict__ pre_part,
               const float* __restrict__ b1,
               const float* __restrict__ W2,
               float* __restrict__ cout) {
    __shared__ unsigned short ann_lds[BS * 512]; // 64 KiB, XOR-swizzled bf16
    __shared__ float pre_lds[512];
    __shared__ float w2_lds[512];
    __shared__ float red[4][64];
    __shared__ float p_lds[64];
    __shared__ float md[2];

    int chunk = blockIdx.x;
    int b = blockIdx.y;
    int s0 = chunk * BS;
    int t = threadIdx.x;
    int w = t >> 6;
    int lane = t & 63;
    int sl = lane & 31;   // M/N lane index within 32
    int g  = lane >> 5;   // k-group (0/1)

    // stage pre_lds = b1 + sum of 4 k-split partials; w2_lds
    {
        int h0 = 2 * t;
        float2 pp = *(const float2*)(b1 + h0);
#pragma unroll
        for (int kc = 0; kc < 4; ++kc) {
            float2 pv = *(const float2*)(pre_part + ((size_t)b * 4 + kc) * HID + h0);
            pp.x += pv.x; pp.y += pv.y;
        }
        pre_lds[h0] = pp.x; pre_lds[h0 + 1] = pp.y;
        float2 wv = *(const float2*)(W2 + h0);
        w2_lds[h0] = wv.x; w2_lds[h0 + 1] = wv.y;
    }

    // stage ann tile (64 rows x 512) -> bf16 LDS, swizzle byte ^= (row&7)<<4
    const float* abase = ann + ((size_t)b * SEQ + s0) * 512;
#pragma unroll
    for (int i = 0; i < 16; ++i) {
        int c = t + i * 256;
        int row = c >> 6;
        int k8 = (c & 63) << 3;
        const float4* src = (const float4*)(abase + (size_t)row * 512 + k8);
        float4 f0 = src[0], f1 = src[1];
        uint4 pk;
        pk.x = (unsigned)f2bf(f0.x) | ((unsigned)f2bf(f0.y) << 16);
        pk.y = (unsigned)f2bf(f0.z) | ((unsigned)f2bf(f0.w) << 16);
        pk.z = (unsigned)f2bf(f1.x) | ((unsigned)f2bf(f1.y) << 16);
        pk.w = (unsigned)f2bf(f1.z) | ((unsigned)f2bf(f1.w) << 16);
        unsigned boff = ((unsigned)(row * 512 + k8) * 2u) ^ ((unsigned)(row & 7) << 4);
        *(uint4*)((char*)ann_lds + boff) = pk;
    }
    __syncthreads();

    float score_p0 = 0.f, score_p1 = 0.f;
#pragma unroll 1
    for (int si = 0; si < 4; ++si) {
        int h_base = (si * 4 + w) * 32;           // each (si,w) -> unique 32-h slice
        bf16x8 afr[32];
        const unsigned short* wbase = w1at + (size_t)(h_base + sl) * 512 + g * 8;
#pragma unroll
        for (int ks = 0; ks < 32; ++ks)
            afr[ks] = *(const bf16x8*)(wbase + ks * 16);
#pragma unroll 1
        for (int st = 0; st < 2; ++st) {
            int srow = st * 32 + sl;
            unsigned base_elem = (unsigned)(srow * 512 + g * 8);
            unsigned swz = (unsigned)(srow & 7) << 4;
            f32x16 acc;
#pragma unroll
            for (int r = 0; r < 16; ++r) acc[r] = 0.f;
#pragma unroll
            for (int ks = 0; ks < 32; ++ks) {
                unsigned boff = ((base_elem + (unsigned)(ks * 16)) * 2u) ^ swz;
                bf16x8 bfr = *(const bf16x8*)((const char*)ann_lds + boff);
                acc = __builtin_amdgcn_mfma_f32_32x32x16_bf16(afr[ks], bfr, acc, 0, 0, 0);
            }
            // epilogue: tanh + dot with w2 over this wave's 16 rows (per k-group)
            float sp = 0.f;
#pragma unroll
            for (int r = 0; r < 16; ++r) {
                int hl = (r & 3) + 8 * (r >> 2) + 4 * g;
                int h = h_base + hl;
                float v = acc[r] + pre_lds[h];
                float e = __expf(2.f * v);
                float th = 1.f - __fdividef(2.f, e + 1.f);
                sp += w2_lds[h] * th;
            }
            if (st == 0) score_p0 += sp; else score_p1 += sp;
        }
    }
    // combine the two k-groups (complementary h rows), then cross-wave via LDS
    score_p0 += __shfl_xor(score_p0, 32);
    score_p1 += __shfl_xor(score_p1, 32);
    if (lane < 32) {
        red[w][lane]      = score_p0;
        red[w][32 + lane] = score_p1;
    }
    __syncthreads();

    if (w == 0) {  // wave 0: assemble 64 scores, block-local softmax
        float sc = red[0][lane] + red[1][lane] + red[2][lane] + red[3][lane];
        float m = sc;
#pragma unroll
        for (int off = 32; off; off >>= 1) m = fmaxf(m, __shfl_xor(m, off));
        float p = __expf(sc - m);
        float d = p;
#pragma unroll
        for (int off = 32; off; off >>= 1) d += __shfl_xor(d, off);
        p_lds[lane] = p;
        if (lane == 0) { md[0] = m; md[1] = d; }
    }
    __syncthreads();

    // partial context numerator from the staged bf16 tile
    float na = 0.f, nb = 0.f;
    int a0 = t * 2;
#pragma unroll 4
    for (int s = 0; s < BS; ++s) {
        float pv = p_lds[s];
        unsigned boff = ((unsigned)(s * 512 + a0) * 2u) ^ ((unsigned)(s & 7) << 4);
        unsigned pair = *(const unsigned*)((const char*)ann_lds + boff);
        float lo = __uint_as_float(pair << 16);
        float hi = __uint_as_float(pair & 0xFFFF0000u);
        na += pv * lo;
        nb += pv * hi;
    }
    float* cb = cout + (size_t)(b * NCHUNK + chunk) * CH_STRIDE;
    cb[2 + a0] = na;
    cb[3 + a0] = nb;
    if (t == 0) { cb[0] = md[0]; cb[1] = md[1]; }
}

// ---- Kernel 4: rescale chunk partials by global max, normalize, write context ----
__global__ void finalize_ctx(const float* __restrict__ cout,
                             float* __restrict__ out) {
    __shared__ float scale[NCHUNK];
    __shared__ float stats[2];
    int b = blockIdx.x;
    int t = threadIdx.x;
    if (t < 64) {
        const float* cb = cout + (size_t)(b * NCHUNK + t) * CH_STRIDE;
        float m = cb[0], d = cb[1];
        float M = m;
#pragma unroll
        for (int off = 32; off; off >>= 1) M = fmaxf(M, __shfl_xor(M, off));
        float sc = __expf(m - M);
        scale[t] = sc;
        float dd = sc * d;
#pragma unroll
        for (int off = 32; off; off >>= 1) dd += __shfl_xor(dd, off);
        if (t == 0) { stats[0] = M; stats[1] = dd; }
    }
    __syncthreads();
    float inv = 1.f / stats[1];
    int a0 = 2 * t;
    float ax = 0.f, ay = 0.f;
    for (int c = 0; c < NCHUNK; ++c) {
        float sc = scale[c];
        const float2 nv = *(const float2*)(cout + (size_t)(b * NCHUNK + c) * CH_STRIDE + 2 + a0);
        ax += sc * nv.x;
        ay += sc * nv.y;
    }
    out[(size_t)b * 512 + a0]     = ax * inv;
    out[(size_t)b * 512 + a0 + 1] = ay * inv;
}

extern "C" void kernel_launch(void* const* d_in, const int* in_sizes, int n_in,
                              void* d_out, int out_size, void* d_ws, size_t ws_size,
                              hipStream_t stream) {
    (void)in_sizes; (void)n_in; (void)out_size; (void)ws_size;
    const float* prev = (const float*)d_in[0];
    const float* ann  = (const float*)d_in[1];
    const float* W1   = (const float*)d_in[2];
    const float* b1   = (const float*)d_in[3];
    const float* W2   = (const float*)d_in[4];
    // b2 (d_in[5]) is a constant shift on scores -> cancels in softmax; unused.
    float* out = (float*)d_out;

    char* ws = (char*)d_ws;
    unsigned short* w1at = (unsigned short*)ws;               // 512*512*2 = 524288 B
    float* pre_part = (float*)(ws + 524288);                  // 32*4*512*4 = 262144 B
    float* cout     = (float*)(ws + 524288 + 262144);         // 32*64*514*4 B

    transpose_w1a<<<dim3(8, 8), dim3(256), 0, stream>>>(W1, w1at);
    pre_partial<<<dim3(4, NB), dim3(256), 0, stream>>>(prev, W1, pre_part);
    score_ctx<<<dim3(NCHUNK, NB), dim3(256), 0, stream>>>(ann, w1at, pre_part, b1, W2, cout);
    finalize_ctx<<<dim3(NB), dim3(256), 0, stream>>>(cout, out);
}